// Round 16
// baseline (130.514 us; speedup 1.0000x reference)
//
#include <hip/hip_runtime.h>
#include <math.h>

// SigmaMoE bf16-MFMA version, round 16.
// = R12 (best, 123.4us) with ONE change: gemm2 -> 128x256 tiles (R14's
// correctness-verified version): 512 thr/8 waves, grid 1024; S re-staging
// 8x -> 4x, tile prologues 4096 -> 1024, staged bytes/MFMA 384 -> 192.
// gemm1 (128x64, BK=64) and all other kernels byte-identical to R12.

constexpr int NTOK = 8192;
constexpr int DM   = 1024;
constexpr int NE   = 16;
constexpr int EH   = 256;
constexpr int TK   = 4;
constexpr int CAP  = 8192;

typedef __attribute__((ext_vector_type(8))) short short8;
typedef __attribute__((ext_vector_type(4))) float f32x4;

#define MFMA16(a, b, c) __builtin_amdgcn_mfma_f32_16x16x32_bf16(a, b, c, 0, 0, 0)

__device__ __forceinline__ void gload_lds16(const void* g, void* l) {
    __builtin_amdgcn_global_load_lds(
        (const __attribute__((address_space(1))) void*)g,
        (__attribute__((address_space(3))) void*)l, 16, 0, 0);
}

__device__ __forceinline__ unsigned short f2bf(float f) {
    union { float f; unsigned int u; } x; x.f = f;
    unsigned int r = x.u + 0x7fffu + ((x.u >> 16) & 1u);  // RNE
    return (unsigned short)(r >> 16);
}
__device__ __forceinline__ float bf2f(unsigned short b) {
    union { unsigned int u; float f; } x; x.u = ((unsigned int)b) << 16;
    return x.f;
}

// ---------------- fused convert + routing (atomic-free) ----------------
__global__ __launch_bounds__(256) void route_conv_kernel(
    const float* __restrict__ x, const float* __restrict__ esel,
    const float* __restrict__ rscale,
    unsigned short* __restrict__ xb,
    int4* __restrict__ sel4, float* __restrict__ wtk)
{
    __shared__ float Es[NE * DM];   // 64KB
    int tid = threadIdx.x;

    {
        const float4* src = (const float4*)esel;
        float4* dst = (float4*)Es;
        #pragma unroll
        for (int j = 0; j < 16; ++j) dst[tid + j * 256] = src[tid + j * 256];
    }
    __syncthreads();

    int t    = blockIdx.x * 8 + (tid >> 5);
    int l32  = tid & 31;

    float acc[NE];
    #pragma unroll
    for (int e = 0; e < NE; ++e) acc[e] = 0.f;

    const float4* x4 = (const float4*)(x + (size_t)t * DM);
    const float4* E4 = (const float4*)Es;
    #pragma unroll
    for (int i4 = 0; i4 < 8; ++i4) {
        int d4 = i4 * 32 + l32;
        float4 xv = x4[d4];
        ushort4 cb = { f2bf(xv.x), f2bf(xv.y), f2bf(xv.z), f2bf(xv.w) };
        *(ushort4*)(xb + (size_t)t * DM + d4 * 4) = cb;
        #pragma unroll
        for (int e = 0; e < NE; ++e) {
            float4 wv = E4[e * 256 + d4];
            acc[e] = fmaf(xv.x, wv.x, acc[e]);
            acc[e] = fmaf(xv.y, wv.y, acc[e]);
            acc[e] = fmaf(xv.z, wv.z, acc[e]);
            acc[e] = fmaf(xv.w, wv.w, acc[e]);
        }
    }

    #pragma unroll
    for (int off = 16; off; off >>= 1)
        #pragma unroll
        for (int e = 0; e < NE; ++e)
            acc[e] += __shfl_xor(acc[e], off, 32);

    if (l32 == 0) {
        float p[NE];
        #pragma unroll
        for (int e = 0; e < NE; ++e) p[e] = 1.0f / (1.0f + expf(-acc[e]));

        int   sel_e[TK];
        float sel_p[TK];
        float sum = 0.f;
        #pragma unroll
        for (int k = 0; k < TK; ++k) {
            float best = -INFINITY; int be = NE;
            #pragma unroll
            for (int e = 0; e < NE; ++e) {
                bool take = p[e] > best;
                best = take ? p[e] : best;
                be   = take ? e    : be;
            }
            sel_e[k] = be; sel_p[k] = best; sum += best;
            #pragma unroll
            for (int e = 0; e < NE; ++e) p[e] = (e == be) ? -INFINITY : p[e];
        }

        float wsc = rscale[0] / fmaxf(sum, 1e-9f);
        int4 s = { sel_e[0], sel_e[1], sel_e[2], sel_e[3] };
        sel4[t] = s;
        float4 wv = { sel_p[0] * wsc, sel_p[1] * wsc,
                      sel_p[2] * wsc, sel_p[3] * wsc };
        *(float4*)(wtk + t * TK) = wv;
    }
}

// ---------------- compact: per-expert lists, atomic-free ----------------
__global__ __launch_bounds__(1024) void compact_kernel(
    const int4* __restrict__ sel4, int* __restrict__ counts,
    int* __restrict__ lpk)
{
    __shared__ int wsum[16];
    int e    = blockIdx.x;
    int tid  = threadIdx.x;
    int w    = tid >> 6;
    int lane = tid & 63;

    int base = 0;
    for (int c = 0; c < NTOK; c += 1024) {
        int t = c + tid;
        int4 s = sel4[t];
        int k = -1;
        if      (s.x == e) k = 0;
        else if (s.y == e) k = 1;
        else if (s.z == e) k = 2;
        else if (s.w == e) k = 3;
        unsigned long long m = __ballot(k >= 0);
        int rank = __popcll(m & ((1ull << lane) - 1ull));
        if (lane == 63) wsum[w] = __popcll(m);
        __syncthreads();
        int prefix = 0, total = 0;
        #pragma unroll
        for (int i = 0; i < 16; ++i) {
            int v = wsum[i];
            prefix += (i < w) ? v : 0;
            total  += v;
        }
        if (k >= 0) lpk[e * CAP + base + prefix + rank] = t * TK + k;
        base += total;
        __syncthreads();
    }
    if (tid == 0) counts[e] = base;
}

// plain transpose: in [E][R][C] f32 -> out [E][C][R] bf16
__global__ __launch_bounds__(256) void trans_kernel(
    const float* __restrict__ in, unsigned short* __restrict__ outp, int R, int C)
{
    __shared__ float T[32][33];
    int e = blockIdx.z;
    int r0 = blockIdx.y * 32, c0 = blockIdx.x * 32;
    int ri = threadIdx.x >> 3, cq = threadIdx.x & 7;
    float4 v = *(const float4*)(in + ((size_t)e * R + r0 + ri) * C + c0 + cq * 4);
    T[ri][cq * 4 + 0] = v.x; T[ri][cq * 4 + 1] = v.y;
    T[ri][cq * 4 + 2] = v.z; T[ri][cq * 4 + 3] = v.w;
    __syncthreads();
    int ci = threadIdx.x >> 3, rq = threadIdx.x & 7;
    ushort4 o = { f2bf(T[rq * 4 + 0][ci]), f2bf(T[rq * 4 + 1][ci]),
                  f2bf(T[rq * 4 + 2][ci]), f2bf(T[rq * 4 + 3][ci]) };
    *(ushort4*)(outp + ((size_t)e * C + c0 + ci) * R + r0 + rq * 4) = o;
}

// values [E][256 k][1024 d] -> vtb [E][1024 d][256 p] with k-permutation
// p = (k>>6)*64 + (k&15)*4 + ((k&63)>>4)  (matches S's 64-block pack)
__global__ __launch_bounds__(256) void transV_kernel(
    const float* __restrict__ in, unsigned short* __restrict__ outp)
{
    __shared__ float T[64][33];
    int e  = blockIdx.z;
    int c0 = blockIdx.x * 32;       // d base
    int r0 = blockIdx.y * 64;       // k base
    int tid = threadIdx.x;
    int kin = tid >> 3, cq = tid & 7;
    {
        float4 v0 = *(const float4*)(in + ((size_t)e * EH + r0 + kin) * DM + c0 + cq * 4);
        float4 v1 = *(const float4*)(in + ((size_t)e * EH + r0 + kin + 32) * DM + c0 + cq * 4);
        T[kin][cq * 4 + 0] = v0.x; T[kin][cq * 4 + 1] = v0.y;
        T[kin][cq * 4 + 2] = v0.z; T[kin][cq * 4 + 3] = v0.w;
        T[kin + 32][cq * 4 + 0] = v1.x; T[kin + 32][cq * 4 + 1] = v1.y;
        T[kin + 32][cq * 4 + 2] = v1.z; T[kin + 32][cq * 4 + 3] = v1.w;
    }
    __syncthreads();
    #pragma unroll
    for (int uu = 0; uu < 2; ++uu) {
        int u = tid + uu * 256;
        int d = u >> 4, lm = u & 15;
        ushort4 o = { f2bf(T[lm][d]), f2bf(T[lm + 16][d]),
                      f2bf(T[lm + 32][d]), f2bf(T[lm + 48][d]) };
        *(ushort4*)(outp + (size_t)e * DM * EH + (size_t)(c0 + d) * EH + r0 + lm * 4) = o;
    }
}

// ---------------- gemm1: S = relu(Xg @ K_e), 128x64 tiles, BK=64 (R12) ----------------
__global__ __launch_bounds__(256, 4) void gemm1_kernel(
    const unsigned short* __restrict__ xb,
    const unsigned short* __restrict__ ktb,   // [E][256 h][1024 k]
    const int* __restrict__ counts, const int* __restrict__ lpk,
    unsigned short* __restrict__ S)           // [gslot][256] (64-block permuted)
{
    __shared__ __align__(16) char L[25088];
    char* const Ab = L;                 // 16KB [128][64] bf16, swizzled
    char* const Bb = L + 16384;         // 8KB  [64][64]
    int* const stok = (int*)(L + 24576);

    int tid = threadIdx.x, lane = tid & 63, w = tid >> 6;
    int lm = lane & 15, q = lane >> 4;

    int xp = blockIdx.x & 7, j0 = blockIdx.x >> 3;   // j0 0..127
    int e0 = xp * 2;
    int c0n = counts[e0], c1n = counts[e0 + 1];
    int n0 = (c0n + 127) >> 7, n1 = (c1n + 127) >> 7;
    int ntot = (n0 + n1) * 4;
    int gb0 = 0;
    for (int i = 0; i < e0; ++i) gb0 += ((counts[i] + 127) >> 7) << 7;
    int gb1 = gb0 + (n0 << 7);

    for (int jt = j0; jt < ntot; jt += 128) {
        int e, mt, nt, cnt, gb;
        if (jt < n0 * 4) { e = e0;     mt = jt >> 2;  nt = jt & 3;  cnt = c0n; gb = gb0; }
        else { int j2 = jt - n0 * 4; e = e0 + 1; mt = j2 >> 2; nt = j2 & 3; cnt = c1n; gb = gb1; }

        __syncthreads();
        if (tid < 128) {
            int s = mt * 128 + tid;
            stok[tid] = (s < cnt) ? (lpk[e * CAP + s] >> 2) : 0;
        }
        __syncthreads();

        const unsigned short* kte = ktb + (size_t)e * EH * DM + (size_t)(nt * 64) * DM;

        f32x4 zero = {0.f, 0.f, 0.f, 0.f};
        f32x4 acc[2][4];
        #pragma unroll
        for (int mi = 0; mi < 2; ++mi)
            #pragma unroll
            for (int ni = 0; ni < 4; ++ni) acc[mi][ni] = zero;

        for (int ks = 0; ks < 16; ++ks) {
            if (ks) __syncthreads();
            #pragma unroll
            for (int c = 0; c < 4; ++c) {          // A: 16KB
                int pos = c * 4096 + w * 1024;
                int row = (pos >> 7) + (lane >> 3);
                int ce  = (((lane & 7) * 16) ^ ((row & 7) << 4)) >> 1;
                gload_lds16(xb + (size_t)stok[row] * DM + ks * 64 + ce, Ab + pos);
            }
            #pragma unroll
            for (int c = 0; c < 2; ++c) {          // B: 8KB
                int pos = c * 4096 + w * 1024;
                int row = (pos >> 7) + (lane >> 3);
                int ce  = (((lane & 7) * 16) ^ ((row & 7) << 4)) >> 1;
                gload_lds16(kte + (size_t)row * DM + ks * 64 + ce, Bb + pos);
            }
            __syncthreads();
            #pragma unroll
            for (int kk = 0; kk < 2; ++kk) {
                short8 a[2], b[4];
                #pragma unroll
                for (int mi = 0; mi < 2; ++mi) {
                    int row = w * 32 + mi * 16 + lm;
                    a[mi] = *(const short8*)(Ab + row * 128 +
                             ((kk * 64 + q * 16) ^ ((row & 7) << 4)));
                }
                #pragma unroll
                for (int ni = 0; ni < 4; ++ni) {
                    int row = ni * 16 + lm;
                    b[ni] = *(const short8*)(Bb + row * 128 +
                             ((kk * 64 + q * 16) ^ ((row & 7) << 4)));
                }
                __builtin_amdgcn_s_setprio(1);
                #pragma unroll
                for (int mi = 0; mi < 2; ++mi)
                    #pragma unroll
                    for (int ni = 0; ni < 4; ++ni)
                        acc[mi][ni] = MFMA16(a[mi], b[ni], acc[mi][ni]);
                __builtin_amdgcn_s_setprio(0);
            }
        }

        // epilogue: relu + packed uint2 into permuted 64-block nt
        #pragma unroll
        for (int mi = 0; mi < 2; ++mi)
            #pragma unroll
            for (int r = 0; r < 4; ++r) {
                int gslot = gb + mt * 128 + w * 32 + mi * 16 + q * 4 + r;
                unsigned int lo = (unsigned int)f2bf(fmaxf(acc[mi][0][r], 0.f)) |
                                  ((unsigned int)f2bf(fmaxf(acc[mi][1][r], 0.f)) << 16);
                unsigned int hi = (unsigned int)f2bf(fmaxf(acc[mi][2][r], 0.f)) |
                                  ((unsigned int)f2bf(fmaxf(acc[mi][3][r], 0.f)) << 16);
                uint2 pv = { lo, hi };
                *(uint2*)(S + (size_t)gslot * EH + nt * 64 + lm * 4) = pv;
            }
    }
}

// ---------------- gemm2: oscr = S @ V_e, 128x256 tiles, BK=64, K=256 (R14) ----------------
// 512 threads / 8 waves; wave (wm,wn) owns 64 tok x 64 d; nt in 0..3.
template<int USE_SCRATCH>
__global__ __launch_bounds__(512, 2) void gemm2_kernel(
    const unsigned short* __restrict__ S,     // [gslot][256] permuted
    const unsigned short* __restrict__ vtb,   // [E][1024 d][256 p] permuted-k
    const int* __restrict__ counts, const int* __restrict__ lpk,
    const float* __restrict__ wtk,
    unsigned short* __restrict__ oscr,        // [NTOK*TK+128][1024] permuted
    float* __restrict__ out)
{
    __shared__ __align__(16) char L[50688];
    char* const Ab = L;                 // 16KB [128][64]
    char* const Bb = L + 16384;         // 32KB [256][64]
    int*   const spk  = (int*)(L + 49152);
    int*   const stok = (int*)(L + 49664);
    float* const sw   = (float*)(L + 50176);

    int tid = threadIdx.x, lane = tid & 63, w = tid >> 6;
    int lm = lane & 15, q = lane >> 4;
    int wm = w >> 2, wn = w & 3;

    int xp = blockIdx.x & 7, j0 = blockIdx.x >> 3;   // grid 1024 -> j0 0..127
    int e0 = xp * 2;
    int c0n = counts[e0], c1n = counts[e0 + 1];
    int m0 = (c0n + 127) >> 7, m1 = (c1n + 127) >> 7;
    int ntot = (m0 + m1) * 4;
    int gb0 = 0;
    for (int i = 0; i < e0; ++i) gb0 += ((counts[i] + 127) >> 7) << 7;
    int gb1 = gb0 + (m0 << 7);

    for (int jt = j0; jt < ntot; jt += 128) {
        int e, mt, nt, cnt, gb;
        if (jt < m0 * 4) { e = e0;     mt = jt >> 2;  nt = jt & 3;  cnt = c0n; gb = gb0; }
        else { int j2 = jt - m0 * 4; e = e0 + 1; mt = j2 >> 2; nt = j2 & 3; cnt = c1n; gb = gb1; }

        __syncthreads();
        if (tid < 128) {
            int s = mt * 128 + tid;
            if (s < cnt) {
                int pk = lpk[e * CAP + s];
                spk[tid] = pk;
                if (!USE_SCRATCH) { stok[tid] = pk >> 2; sw[tid] = wtk[pk]; }
            } else {
                spk[tid] = NTOK * TK;
                if (!USE_SCRATCH) { stok[tid] = 0; sw[tid] = 0.f; }
            }
        }
        __syncthreads();

        const unsigned short* Se  = S + (size_t)(gb + mt * 128) * EH;
        const unsigned short* vte = vtb + (size_t)e * DM * EH + (size_t)(nt * 256) * EH;

        f32x4 zero = {0.f, 0.f, 0.f, 0.f};
        f32x4 acc[4][4];
        #pragma unroll
        for (int mi = 0; mi < 4; ++mi)
            #pragma unroll
            for (int ni = 0; ni < 4; ++ni) acc[mi][ni] = zero;

        #pragma unroll
        for (int ks = 0; ks < 4; ++ks) {
            if (ks) __syncthreads();
            #pragma unroll
            for (int c = 0; c < 2; ++c) {          // A: 16KB
                int pos = c * 8192 + w * 1024;
                int row = (pos >> 7) + (lane >> 3);
                int ce  = (((lane & 7) * 16) ^ ((row & 7) << 4)) >> 1;
                gload_lds16(Se + (size_t)row * EH + ks * 64 + ce, Ab + pos);
            }
            #pragma unroll
            for (int c = 0; c < 4; ++c) {          // B: 32KB
                int pos = c * 8192 + w * 1024;
                int row = (pos >> 7) + (lane >> 3);
                int ce  = (((lane & 7) * 16) ^ ((row & 7) << 4)) >> 1;
                gload_lds16(vte + (size_t)row * EH + ks * 64 + ce, Bb + pos);
            }
            __syncthreads();
            #pragma unroll
            for (int kk = 0; kk < 2; ++kk) {
                short8 a[4], b[4];
                #pragma unroll
                for (int mi = 0; mi < 4; ++mi) {
                    int row = wm * 64 + mi * 16 + lm;
                    a[mi] = *(const short8*)(Ab + row * 128 +
                             ((kk * 64 + q * 16) ^ ((row & 7) << 4)));
                }
                #pragma unroll
                for (int ni = 0; ni < 4; ++ni) {
                    int row = wn * 64 + ni * 16 + lm;
                    b[ni] = *(const short8*)(Bb + row * 128 +
                             ((kk * 64 + q * 16) ^ ((row & 7) << 4)));
                }
                __builtin_amdgcn_s_setprio(1);
                #pragma unroll
                for (int mi = 0; mi < 4; ++mi)
                    #pragma unroll
                    for (int ni = 0; ni < 4; ++ni)
                        acc[mi][ni] = MFMA16(a[mi], b[ni], acc[mi][ni]);
                __builtin_amdgcn_s_setprio(0);
            }
        }

        int cb64 = nt * 4 + wn;
        #pragma unroll
        for (int mi = 0; mi < 4; ++mi)
            #pragma unroll
            for (int r = 0; r < 4; ++r) {
                int slot = wm * 64 + mi * 16 + q * 4 + r;
                if (USE_SCRATCH) {
                    int pk = spk[slot];
                    unsigned int lo = (unsigned int)f2bf(acc[mi][0][r]) |
                                      ((unsigned int)f2bf(acc[mi][1][r]) << 16);
                    unsigned int hi = (unsigned int)f2bf(acc[mi][2][r]) |
                                      ((unsigned int)f2bf(acc[mi][3][r]) << 16);
                    uint2 pv = { lo, hi };
                    *(uint2*)(oscr + (size_t)pk * DM + cb64 * 64 + lm * 4) = pv;
                } else {
                    #pragma unroll
                    for (int ni = 0; ni < 4; ++ni) {
                        int d = cb64 * 64 + ni * 16 + lm;
                        atomicAdd(out + (size_t)stok[slot] * DM + d,
                                  sw[slot] * acc[mi][ni][r]);
                    }
                }
            }
    }
}

// ---------------- combine (inverts the permuted oscr layout) ----------------
__global__ __launch_bounds__(256) void combine_kernel(
    const unsigned short* __restrict__ oscr, const float* __restrict__ wtk,
    float* __restrict__ out)
{
    int t   = blockIdx.x * 2 + (threadIdx.x >> 7);
    int l   = threadIdx.x & 127;
    int blk = l >> 3;
    int lm2 = l & 7;
    float o[8] = {0.f, 0.f, 0.f, 0.f, 0.f, 0.f, 0.f, 0.f};
    #pragma unroll
    for (int k = 0; k < TK; ++k) {
        float wv = wtk[t * TK + k];
        uint4 qv = *(const uint4*)(oscr + (size_t)(t * TK + k) * DM +
                                   blk * 64 + lm2 * 8);
        unsigned int us[4] = { qv.x, qv.y, qv.z, qv.w };
        #pragma unroll
        for (int j = 0; j < 4; ++j) {
            o[j * 2 + 0] = fmaf(wv, bf2f((unsigned short)(us[j] & 0xffff)), o[j * 2 + 0]);
            o[j * 2 + 1] = fmaf(wv, bf2f((unsigned short)(us[j] >> 16)),    o[j * 2 + 1]);
        }
    }
    float* ob = out + (size_t)t * DM + blk * 64 + 2 * lm2;
    #pragma unroll
    for (int ni = 0; ni < 4; ++ni) {
        float2 f2 = { o[ni], o[ni + 4] };
        *(float2*)(ob + ni * 16) = f2;
    }
}

extern "C" void kernel_launch(void* const* d_in, const int* in_sizes, int n_in,
                              void* d_out, int out_size, void* d_ws, size_t ws_size,
                              hipStream_t stream) {
    const float* x      = (const float*)d_in[0];
    const float* esel   = (const float*)d_in[1];
    const float* keys   = (const float*)d_in[2];
    const float* values = (const float*)d_in[3];
    const float* rscale = (const float*)d_in[4];
    float* out = (float*)d_out;

    char* ws = (char*)d_ws;
    size_t o = 0;
    auto alloc = [&](size_t sz) { size_t r = o; o = (o + sz + 255) & ~(size_t)255; return r; };
    size_t o_counts = alloc(NE * 4);
    size_t o_lpk    = alloc((size_t)NE * CAP * 4);
    size_t o_sel4   = alloc((size_t)NTOK * 16);
    size_t o_wtk    = alloc((size_t)NTOK * TK * 4);
    size_t o_xb     = alloc((size_t)NTOK * DM * 2);
    size_t o_ktb    = alloc((size_t)NE * EH * DM * 2);
    size_t o_vtb    = alloc((size_t)NE * DM * EH * 2);
    size_t o_S      = alloc(((size_t)NTOK * TK + NE * 128) * EH * 2);
    size_t need_small = o;
    size_t o_oscr   = alloc(((size_t)NTOK * TK + 128) * DM * 2);
    size_t need_full = o;

    int*            counts = (int*)(ws + o_counts);
    int*            lpk    = (int*)(ws + o_lpk);
    int4*           sel4   = (int4*)(ws + o_sel4);
    float*          wtk    = (float*)(ws + o_wtk);
    unsigned short* xb     = (unsigned short*)(ws + o_xb);
    unsigned short* ktb    = (unsigned short*)(ws + o_ktb);
    unsigned short* vtb    = (unsigned short*)(ws + o_vtb);
    unsigned short* Sbuf   = (unsigned short*)(ws + o_S);
    unsigned short* oscr   = (unsigned short*)(ws + o_oscr);

    bool use_scratch = ws_size >= need_full;
    (void)need_small;

    if (!use_scratch)
        hipMemsetAsync(d_out, 0, (size_t)out_size * sizeof(float), stream);

    route_conv_kernel<<<NTOK / 8, 256, 0, stream>>>(x, esel, rscale, xb,
                                                    sel4, wtk);
    compact_kernel<<<NE, 1024, 0, stream>>>(sel4, counts, lpk);
    // keys [E][1024 k][256 h] -> ktb [E][256 h][1024 k]
    trans_kernel<<<dim3(EH / 32, DM / 32, NE), 256, 0, stream>>>(keys, ktb, DM, EH);
    // values [E][256 k][1024 d] -> vtb [E][1024 d][256 p] (k-permuted)
    transV_kernel<<<dim3(DM / 32, EH / 64, NE), 256, 0, stream>>>(values, vtb);

    gemm1_kernel<<<1024, 256, 0, stream>>>(xb, ktb, counts, lpk, Sbuf);

    if (use_scratch) {
        gemm2_kernel<1><<<1024, 512, 0, stream>>>(Sbuf, vtb, counts,
                                                  lpk, wtk, oscr, out);
        combine_kernel<<<NTOK / 2, 256, 0, stream>>>(oscr, wtk, out);
    } else {
        gemm2_kernel<0><<<1024, 512, 0, stream>>>(Sbuf, vtb, counts,
                                                  lpk, wtk, oscr, out);
    }
}

// Round 17
// 121.120 us; speedup vs baseline: 1.0776x; 1.0776x over previous
//
#include <hip/hip_runtime.h>
#include <math.h>

// SigmaMoE bf16-MFMA version, round 17.
// = R12 (measured best, 123.4us) with ONE change: trans + transV merged
// into a single transKV_kernel launch (one fewer launch in the serial chain).
// gemm1 (128x64, grid 1024), gemm2 (64x128, grid 4096) byte-identical to R12.

constexpr int NTOK = 8192;
constexpr int DM   = 1024;
constexpr int NE   = 16;
constexpr int EH   = 256;
constexpr int TK   = 4;
constexpr int CAP  = 8192;

typedef __attribute__((ext_vector_type(8))) short short8;
typedef __attribute__((ext_vector_type(4))) float f32x4;

#define MFMA16(a, b, c) __builtin_amdgcn_mfma_f32_16x16x32_bf16(a, b, c, 0, 0, 0)

__device__ __forceinline__ void gload_lds16(const void* g, void* l) {
    __builtin_amdgcn_global_load_lds(
        (const __attribute__((address_space(1))) void*)g,
        (__attribute__((address_space(3))) void*)l, 16, 0, 0);
}

__device__ __forceinline__ unsigned short f2bf(float f) {
    union { float f; unsigned int u; } x; x.f = f;
    unsigned int r = x.u + 0x7fffu + ((x.u >> 16) & 1u);  // RNE
    return (unsigned short)(r >> 16);
}
__device__ __forceinline__ float bf2f(unsigned short b) {
    union { unsigned int u; float f; } x; x.u = ((unsigned int)b) << 16;
    return x.f;
}

// ---------------- fused convert + routing (atomic-free) ----------------
__global__ __launch_bounds__(256) void route_conv_kernel(
    const float* __restrict__ x, const float* __restrict__ esel,
    const float* __restrict__ rscale,
    unsigned short* __restrict__ xb,
    int4* __restrict__ sel4, float* __restrict__ wtk)
{
    __shared__ float Es[NE * DM];   // 64KB
    int tid = threadIdx.x;

    {
        const float4* src = (const float4*)esel;
        float4* dst = (float4*)Es;
        #pragma unroll
        for (int j = 0; j < 16; ++j) dst[tid + j * 256] = src[tid + j * 256];
    }
    __syncthreads();

    int t    = blockIdx.x * 8 + (tid >> 5);
    int l32  = tid & 31;

    float acc[NE];
    #pragma unroll
    for (int e = 0; e < NE; ++e) acc[e] = 0.f;

    const float4* x4 = (const float4*)(x + (size_t)t * DM);
    const float4* E4 = (const float4*)Es;
    #pragma unroll
    for (int i4 = 0; i4 < 8; ++i4) {
        int d4 = i4 * 32 + l32;
        float4 xv = x4[d4];
        ushort4 cb = { f2bf(xv.x), f2bf(xv.y), f2bf(xv.z), f2bf(xv.w) };
        *(ushort4*)(xb + (size_t)t * DM + d4 * 4) = cb;
        #pragma unroll
        for (int e = 0; e < NE; ++e) {
            float4 wv = E4[e * 256 + d4];
            acc[e] = fmaf(xv.x, wv.x, acc[e]);
            acc[e] = fmaf(xv.y, wv.y, acc[e]);
            acc[e] = fmaf(xv.z, wv.z, acc[e]);
            acc[e] = fmaf(xv.w, wv.w, acc[e]);
        }
    }

    #pragma unroll
    for (int off = 16; off; off >>= 1)
        #pragma unroll
        for (int e = 0; e < NE; ++e)
            acc[e] += __shfl_xor(acc[e], off, 32);

    if (l32 == 0) {
        float p[NE];
        #pragma unroll
        for (int e = 0; e < NE; ++e) p[e] = 1.0f / (1.0f + expf(-acc[e]));

        int   sel_e[TK];
        float sel_p[TK];
        float sum = 0.f;
        #pragma unroll
        for (int k = 0; k < TK; ++k) {
            float best = -INFINITY; int be = NE;
            #pragma unroll
            for (int e = 0; e < NE; ++e) {
                bool take = p[e] > best;
                best = take ? p[e] : best;
                be   = take ? e    : be;
            }
            sel_e[k] = be; sel_p[k] = best; sum += best;
            #pragma unroll
            for (int e = 0; e < NE; ++e) p[e] = (e == be) ? -INFINITY : p[e];
        }

        float wsc = rscale[0] / fmaxf(sum, 1e-9f);
        int4 s = { sel_e[0], sel_e[1], sel_e[2], sel_e[3] };
        sel4[t] = s;
        float4 wv = { sel_p[0] * wsc, sel_p[1] * wsc,
                      sel_p[2] * wsc, sel_p[3] * wsc };
        *(float4*)(wtk + t * TK) = wv;
    }
}

// ---------------- compact: per-expert lists, atomic-free ----------------
__global__ __launch_bounds__(1024) void compact_kernel(
    const int4* __restrict__ sel4, int* __restrict__ counts,
    int* __restrict__ lpk)
{
    __shared__ int wsum[16];
    int e    = blockIdx.x;
    int tid  = threadIdx.x;
    int w    = tid >> 6;
    int lane = tid & 63;

    int base = 0;
    for (int c = 0; c < NTOK; c += 1024) {
        int t = c + tid;
        int4 s = sel4[t];
        int k = -1;
        if      (s.x == e) k = 0;
        else if (s.y == e) k = 1;
        else if (s.z == e) k = 2;
        else if (s.w == e) k = 3;
        unsigned long long m = __ballot(k >= 0);
        int rank = __popcll(m & ((1ull << lane) - 1ull));
        if (lane == 63) wsum[w] = __popcll(m);
        __syncthreads();
        int prefix = 0, total = 0;
        #pragma unroll
        for (int i = 0; i < 16; ++i) {
            int v = wsum[i];
            prefix += (i < w) ? v : 0;
            total  += v;
        }
        if (k >= 0) lpk[e * CAP + base + prefix + rank] = t * TK + k;
        base += total;
        __syncthreads();
    }
    if (tid == 0) counts[e] = base;
}

// ---------------- merged weight transposes (one launch) ----------------
// blocks [0,4096): keys [E][1024 k][256 h] -> ktb [E][256 h][1024 k]
// blocks [4096,6144): values [E][256 k][1024 d] -> vtb [E][1024 d][256 p],
//   p = (k>>6)*64 + (k&15)*4 + ((k&63)>>4)  (matches S's 64-block pack)
__global__ __launch_bounds__(256) void transKV_kernel(
    const float* __restrict__ keys, const float* __restrict__ values,
    unsigned short* __restrict__ ktb, unsigned short* __restrict__ vtb)
{
    int b = blockIdx.x;
    int tid = threadIdx.x;
    if (b < 4096) {
        // ---- keys transpose (R=DM rows in, C=EH cols in) ----
        __shared__ float T[32][33];
        int bx = b & 7, by = (b >> 3) & 31, e = b >> 8;
        int r0 = by * 32, c0 = bx * 32;
        int ri = tid >> 3, cq = tid & 7;
        float4 v = *(const float4*)(keys + ((size_t)e * DM + r0 + ri) * EH + c0 + cq * 4);
        T[ri][cq * 4 + 0] = v.x; T[ri][cq * 4 + 1] = v.y;
        T[ri][cq * 4 + 2] = v.z; T[ri][cq * 4 + 3] = v.w;
        __syncthreads();
        int ci = tid >> 3, rq = tid & 7;
        ushort4 o = { f2bf(T[rq * 4 + 0][ci]), f2bf(T[rq * 4 + 1][ci]),
                      f2bf(T[rq * 4 + 2][ci]), f2bf(T[rq * 4 + 3][ci]) };
        *(ushort4*)(ktb + ((size_t)e * EH + c0 + ci) * DM + r0 + rq * 4) = o;
    } else {
        // ---- values transpose with k-permutation ----
        __shared__ float T[64][33];
        int b2 = b - 4096;
        int bx = b2 & 31, by = (b2 >> 5) & 3, e = b2 >> 7;
        int c0 = bx * 32;       // d base
        int r0 = by * 64;       // k base
        int kin = tid >> 3, cq = tid & 7;
        {
            float4 v0 = *(const float4*)(values + ((size_t)e * EH + r0 + kin) * DM + c0 + cq * 4);
            float4 v1 = *(const float4*)(values + ((size_t)e * EH + r0 + kin + 32) * DM + c0 + cq * 4);
            T[kin][cq * 4 + 0] = v0.x; T[kin][cq * 4 + 1] = v0.y;
            T[kin][cq * 4 + 2] = v0.z; T[kin][cq * 4 + 3] = v0.w;
            T[kin + 32][cq * 4 + 0] = v1.x; T[kin + 32][cq * 4 + 1] = v1.y;
            T[kin + 32][cq * 4 + 2] = v1.z; T[kin + 32][cq * 4 + 3] = v1.w;
        }
        __syncthreads();
        #pragma unroll
        for (int uu = 0; uu < 2; ++uu) {
            int u = tid + uu * 256;
            int d = u >> 4, lm = u & 15;
            ushort4 o = { f2bf(T[lm][d]), f2bf(T[lm + 16][d]),
                          f2bf(T[lm + 32][d]), f2bf(T[lm + 48][d]) };
            *(ushort4*)(vtb + (size_t)e * DM * EH + (size_t)(c0 + d) * EH + r0 + lm * 4) = o;
        }
    }
}

// ---------------- gemm1: S = relu(Xg @ K_e), 128x64 tiles, BK=64 (R12) ----------------
__global__ __launch_bounds__(256, 4) void gemm1_kernel(
    const unsigned short* __restrict__ xb,
    const unsigned short* __restrict__ ktb,   // [E][256 h][1024 k]
    const int* __restrict__ counts, const int* __restrict__ lpk,
    unsigned short* __restrict__ S)           // [gslot][256] (64-block permuted)
{
    __shared__ __align__(16) char L[25088];
    char* const Ab = L;                 // 16KB [128][64] bf16, swizzled
    char* const Bb = L + 16384;         // 8KB  [64][64]
    int* const stok = (int*)(L + 24576);

    int tid = threadIdx.x, lane = tid & 63, w = tid >> 6;
    int lm = lane & 15, q = lane >> 4;

    int xp = blockIdx.x & 7, j0 = blockIdx.x >> 3;   // j0 0..127
    int e0 = xp * 2;
    int c0n = counts[e0], c1n = counts[e0 + 1];
    int n0 = (c0n + 127) >> 7, n1 = (c1n + 127) >> 7;
    int ntot = (n0 + n1) * 4;
    int gb0 = 0;
    for (int i = 0; i < e0; ++i) gb0 += ((counts[i] + 127) >> 7) << 7;
    int gb1 = gb0 + (n0 << 7);

    for (int jt = j0; jt < ntot; jt += 128) {
        int e, mt, nt, cnt, gb;
        if (jt < n0 * 4) { e = e0;     mt = jt >> 2;  nt = jt & 3;  cnt = c0n; gb = gb0; }
        else { int j2 = jt - n0 * 4; e = e0 + 1; mt = j2 >> 2; nt = j2 & 3; cnt = c1n; gb = gb1; }

        __syncthreads();
        if (tid < 128) {
            int s = mt * 128 + tid;
            stok[tid] = (s < cnt) ? (lpk[e * CAP + s] >> 2) : 0;
        }
        __syncthreads();

        const unsigned short* kte = ktb + (size_t)e * EH * DM + (size_t)(nt * 64) * DM;

        f32x4 zero = {0.f, 0.f, 0.f, 0.f};
        f32x4 acc[2][4];
        #pragma unroll
        for (int mi = 0; mi < 2; ++mi)
            #pragma unroll
            for (int ni = 0; ni < 4; ++ni) acc[mi][ni] = zero;

        for (int ks = 0; ks < 16; ++ks) {
            if (ks) __syncthreads();
            #pragma unroll
            for (int c = 0; c < 4; ++c) {          // A: 16KB
                int pos = c * 4096 + w * 1024;
                int row = (pos >> 7) + (lane >> 3);
                int ce  = (((lane & 7) * 16) ^ ((row & 7) << 4)) >> 1;
                gload_lds16(xb + (size_t)stok[row] * DM + ks * 64 + ce, Ab + pos);
            }
            #pragma unroll
            for (int c = 0; c < 2; ++c) {          // B: 8KB
                int pos = c * 4096 + w * 1024;
                int row = (pos >> 7) + (lane >> 3);
                int ce  = (((lane & 7) * 16) ^ ((row & 7) << 4)) >> 1;
                gload_lds16(kte + (size_t)row * DM + ks * 64 + ce, Bb + pos);
            }
            __syncthreads();
            #pragma unroll
            for (int kk = 0; kk < 2; ++kk) {
                short8 a[2], b[4];
                #pragma unroll
                for (int mi = 0; mi < 2; ++mi) {
                    int row = w * 32 + mi * 16 + lm;
                    a[mi] = *(const short8*)(Ab + row * 128 +
                             ((kk * 64 + q * 16) ^ ((row & 7) << 4)));
                }
                #pragma unroll
                for (int ni = 0; ni < 4; ++ni) {
                    int row = ni * 16 + lm;
                    b[ni] = *(const short8*)(Bb + row * 128 +
                             ((kk * 64 + q * 16) ^ ((row & 7) << 4)));
                }
                __builtin_amdgcn_s_setprio(1);
                #pragma unroll
                for (int mi = 0; mi < 2; ++mi)
                    #pragma unroll
                    for (int ni = 0; ni < 4; ++ni)
                        acc[mi][ni] = MFMA16(a[mi], b[ni], acc[mi][ni]);
                __builtin_amdgcn_s_setprio(0);
            }
        }

        // epilogue: relu + packed uint2 into permuted 64-block nt
        #pragma unroll
        for (int mi = 0; mi < 2; ++mi)
            #pragma unroll
            for (int r = 0; r < 4; ++r) {
                int gslot = gb + mt * 128 + w * 32 + mi * 16 + q * 4 + r;
                unsigned int lo = (unsigned int)f2bf(fmaxf(acc[mi][0][r], 0.f)) |
                                  ((unsigned int)f2bf(fmaxf(acc[mi][1][r], 0.f)) << 16);
                unsigned int hi = (unsigned int)f2bf(fmaxf(acc[mi][2][r], 0.f)) |
                                  ((unsigned int)f2bf(fmaxf(acc[mi][3][r], 0.f)) << 16);
                uint2 pv = { lo, hi };
                *(uint2*)(S + (size_t)gslot * EH + nt * 64 + lm * 4) = pv;
            }
    }
}

// ---------------- gemm2: oscr = S @ V_e, 64x128 tiles, BK=64, K=256 (R12) ----------------
template<int USE_SCRATCH>
__global__ __launch_bounds__(256, 4) void gemm2_kernel(
    const unsigned short* __restrict__ S,     // [gslot][256] permuted
    const unsigned short* __restrict__ vtb,   // [E][1024 d][256 p] permuted-k
    const int* __restrict__ counts, const int* __restrict__ lpk,
    const float* __restrict__ wtk,
    unsigned short* __restrict__ oscr,        // [NTOK*TK+128][1024] permuted
    float* __restrict__ out)
{
    __shared__ __align__(16) char L[25344];
    char* const Ab = L;                 // 8KB  [64][64]
    char* const Bb = L + 8192;          // 16KB [128][64]
    int*   const spk  = (int*)(L + 24576);
    int*   const stok = (int*)(L + 24832);
    float* const sw   = (float*)(L + 25088);

    int tid = threadIdx.x, lane = tid & 63, w = tid >> 6;
    int lm = lane & 15, q = lane >> 4;
    int wm = w >> 1, wn = w & 1;

    int xp = blockIdx.x & 7, j0 = blockIdx.x >> 3;   // grid 4096 -> j0 0..511
    int e0 = xp * 2;
    int c0n = counts[e0], c1n = counts[e0 + 1];
    int m0 = (c0n + 63) >> 6, m1 = (c1n + 63) >> 6;
    int ntot = (m0 + m1) * 8;
    int gb0 = 0;
    for (int i = 0; i < e0; ++i) gb0 += ((counts[i] + 127) >> 7) << 7;
    int gb1 = gb0 + (((c0n + 127) >> 7) << 7);

    for (int jt = j0; jt < ntot; jt += 512) {
        int e, mt, nt, cnt, gb;
        if (jt < m0 * 8) { e = e0;     mt = jt >> 3;  nt = jt & 7;  cnt = c0n; gb = gb0; }
        else { int j2 = jt - m0 * 8; e = e0 + 1; mt = j2 >> 3; nt = j2 & 7; cnt = c1n; gb = gb1; }

        __syncthreads();
        if (tid < 64) {
            int s = mt * 64 + tid;
            if (s < cnt) {
                int pk = lpk[e * CAP + s];
                spk[tid] = pk;
                if (!USE_SCRATCH) { stok[tid] = pk >> 2; sw[tid] = wtk[pk]; }
            } else {
                spk[tid] = NTOK * TK;
                if (!USE_SCRATCH) { stok[tid] = 0; sw[tid] = 0.f; }
            }
        }
        __syncthreads();

        const unsigned short* Se  = S + (size_t)(gb + mt * 64) * EH;
        const unsigned short* vte = vtb + (size_t)e * DM * EH + (size_t)(nt * 128) * EH;

        f32x4 zero = {0.f, 0.f, 0.f, 0.f};
        f32x4 acc[2][4];
        #pragma unroll
        for (int mi = 0; mi < 2; ++mi)
            #pragma unroll
            for (int ni = 0; ni < 4; ++ni) acc[mi][ni] = zero;

        #pragma unroll
        for (int ks = 0; ks < 4; ++ks) {
            if (ks) __syncthreads();
            #pragma unroll
            for (int c = 0; c < 2; ++c) {          // A: 8KB
                int pos = c * 4096 + w * 1024;
                int row = (pos >> 7) + (lane >> 3);
                int ce  = (((lane & 7) * 16) ^ ((row & 7) << 4)) >> 1;
                gload_lds16(Se + (size_t)row * EH + ks * 64 + ce, Ab + pos);
            }
            #pragma unroll
            for (int c = 0; c < 4; ++c) {          // B: 16KB
                int pos = c * 4096 + w * 1024;
                int row = (pos >> 7) + (lane >> 3);
                int ce  = (((lane & 7) * 16) ^ ((row & 7) << 4)) >> 1;
                gload_lds16(vte + (size_t)row * EH + ks * 64 + ce, Bb + pos);
            }
            __syncthreads();
            #pragma unroll
            for (int kk = 0; kk < 2; ++kk) {
                short8 a[2], b[4];
                #pragma unroll
                for (int mi = 0; mi < 2; ++mi) {
                    int row = wm * 32 + mi * 16 + lm;
                    a[mi] = *(const short8*)(Ab + row * 128 +
                             ((kk * 64 + q * 16) ^ ((row & 7) << 4)));
                }
                #pragma unroll
                for (int ni = 0; ni < 4; ++ni) {
                    int row = wn * 64 + ni * 16 + lm;
                    b[ni] = *(const short8*)(Bb + row * 128 +
                             ((kk * 64 + q * 16) ^ ((row & 7) << 4)));
                }
                __builtin_amdgcn_s_setprio(1);
                #pragma unroll
                for (int mi = 0; mi < 2; ++mi)
                    #pragma unroll
                    for (int ni = 0; ni < 4; ++ni)
                        acc[mi][ni] = MFMA16(a[mi], b[ni], acc[mi][ni]);
                __builtin_amdgcn_s_setprio(0);
            }
        }

        int cb64 = nt * 2 + wn;
        #pragma unroll
        for (int mi = 0; mi < 2; ++mi)
            #pragma unroll
            for (int r = 0; r < 4; ++r) {
                int slot = wm * 32 + mi * 16 + q * 4 + r;
                if (USE_SCRATCH) {
                    int pk = spk[slot];
                    unsigned int lo = (unsigned int)f2bf(acc[mi][0][r]) |
                                      ((unsigned int)f2bf(acc[mi][1][r]) << 16);
                    unsigned int hi = (unsigned int)f2bf(acc[mi][2][r]) |
                                      ((unsigned int)f2bf(acc[mi][3][r]) << 16);
                    uint2 pv = { lo, hi };
                    *(uint2*)(oscr + (size_t)pk * DM + cb64 * 64 + lm * 4) = pv;
                } else {
                    #pragma unroll
                    for (int ni = 0; ni < 4; ++ni) {
                        int d = cb64 * 64 + ni * 16 + lm;
                        atomicAdd(out + (size_t)stok[slot] * DM + d,
                                  sw[slot] * acc[mi][ni][r]);
                    }
                }
            }
    }
}

// ---------------- combine (inverts the permuted oscr layout) ----------------
__global__ __launch_bounds__(256) void combine_kernel(
    const unsigned short* __restrict__ oscr, const float* __restrict__ wtk,
    float* __restrict__ out)
{
    int t   = blockIdx.x * 2 + (threadIdx.x >> 7);
    int l   = threadIdx.x & 127;
    int blk = l >> 3;
    int lm2 = l & 7;
    float o[8] = {0.f, 0.f, 0.f, 0.f, 0.f, 0.f, 0.f, 0.f};
    #pragma unroll
    for (int k = 0; k < TK; ++k) {
        float wv = wtk[t * TK + k];
        uint4 qv = *(const uint4*)(oscr + (size_t)(t * TK + k) * DM +
                                   blk * 64 + lm2 * 8);
        unsigned int us[4] = { qv.x, qv.y, qv.z, qv.w };
        #pragma unroll
        for (int j = 0; j < 4; ++j) {
            o[j * 2 + 0] = fmaf(wv, bf2f((unsigned short)(us[j] & 0xffff)), o[j * 2 + 0]);
            o[j * 2 + 1] = fmaf(wv, bf2f((unsigned short)(us[j] >> 16)),    o[j * 2 + 1]);
        }
    }
    float* ob = out + (size_t)t * DM + blk * 64 + 2 * lm2;
    #pragma unroll
    for (int ni = 0; ni < 4; ++ni) {
        float2 f2 = { o[ni], o[ni + 4] };
        *(float2*)(ob + ni * 16) = f2;
    }
}

extern "C" void kernel_launch(void* const* d_in, const int* in_sizes, int n_in,
                              void* d_out, int out_size, void* d_ws, size_t ws_size,
                              hipStream_t stream) {
    const float* x      = (const float*)d_in[0];
    const float* esel   = (const float*)d_in[1];
    const float* keys   = (const float*)d_in[2];
    const float* values = (const float*)d_in[3];
    const float* rscale = (const float*)d_in[4];
    float* out = (float*)d_out;

    char* ws = (char*)d_ws;
    size_t o = 0;
    auto alloc = [&](size_t sz) { size_t r = o; o = (o + sz + 255) & ~(size_t)255; return r; };
    size_t o_counts = alloc(NE * 4);
    size_t o_lpk    = alloc((size_t)NE * CAP * 4);
    size_t o_sel4   = alloc((size_t)NTOK * 16);
    size_t o_wtk    = alloc((size_t)NTOK * TK * 4);
    size_t o_xb     = alloc((size_t)NTOK * DM * 2);
    size_t o_ktb    = alloc((size_t)NE * EH * DM * 2);
    size_t o_vtb    = alloc((size_t)NE * DM * EH * 2);
    size_t o_S      = alloc(((size_t)NTOK * TK + NE * 128) * EH * 2);
    size_t need_small = o;
    size_t o_oscr   = alloc(((size_t)NTOK * TK + 128) * DM * 2);
    size_t need_full = o;

    int*            counts = (int*)(ws + o_counts);
    int*            lpk    = (int*)(ws + o_lpk);
    int4*           sel4   = (int4*)(ws + o_sel4);
    float*          wtk    = (float*)(ws + o_wtk);
    unsigned short* xb     = (unsigned short*)(ws + o_xb);
    unsigned short* ktb    = (unsigned short*)(ws + o_ktb);
    unsigned short* vtb    = (unsigned short*)(ws + o_vtb);
    unsigned short* Sbuf   = (unsigned short*)(ws + o_S);
    unsigned short* oscr   = (unsigned short*)(ws + o_oscr);

    bool use_scratch = ws_size >= need_full;
    (void)need_small;

    if (!use_scratch)
        hipMemsetAsync(d_out, 0, (size_t)out_size * sizeof(float), stream);

    route_conv_kernel<<<NTOK / 8, 256, 0, stream>>>(x, esel, rscale, xb,
                                                    sel4, wtk);
    compact_kernel<<<NE, 1024, 0, stream>>>(sel4, counts, lpk);
    transKV_kernel<<<6144, 256, 0, stream>>>(keys, values, ktb, vtb);

    gemm1_kernel<<<1024, 256, 0, stream>>>(xb, ktb, counts, lpk, Sbuf);

    if (use_scratch) {
        gemm2_kernel<1><<<4096, 256, 0, stream>>>(Sbuf, vtb, counts,
                                                  lpk, wtk, oscr, out);
        combine_kernel<<<NTOK / 2, 256, 0, stream>>>(oscr, wtk, out);
    } else {
        gemm2_kernel<0><<<4096, 256, 0, stream>>>(Sbuf, vtb, counts,
                                                  lpk, wtk, oscr, out);
    }
}